// Round 4
// baseline (178.689 us; speedup 1.0000x reference)
//
#include <hip/hip_runtime.h>

#define NCLS 1000
#define DIM 64
#define DG 8            // dim groups
#define DSUB 8          // dims per group (DG*DSUB == DIM)
#define ACCW 9          // padded class stride in LDS (odd -> conflict-free banks)
#define CHUNKS 64       // row chunks
#define TPB 512

struct Ws {
    float    sums[NCLS * DIM];   // 256000 B
    int      counts[NCLS];       // 4000 B
    double   sumsq;              // 8-aligned
    double   muterm;
    unsigned minkey;
    unsigned pad_;
    float    mu[NCLS * DIM];
    float    sq[NCLS];
};

__device__ __forceinline__ unsigned fkey(float x) {
    unsigned b = __float_as_uint(x);
    return (b & 0x80000000u) ? ~b : (b | 0x80000000u);
}
__device__ __forceinline__ float funkey(unsigned k) {
    return (k & 0x80000000u) ? __uint_as_float(k & 0x7FFFFFFFu)
                             : __uint_as_float(~k);
}

// Main pass: per-class partial sums (dim-split in LDS, odd-padded stride)
// + counts (g==0 blocks) + total sum of squares.
// All float atomics are unsafeAtomicAdd -> native ds_add_f32 / global_atomic_add_f32
// (plain atomicAdd(float*) compiles to a CAS retry loop without -munsafe-fp-atomics).
__global__ __launch_bounds__(TPB, 8) void k_accum(const float* __restrict__ emb,
                                                  const int* __restrict__ tgt,
                                                  int n, Ws* ws) {
    __shared__ float acc[NCLS * ACCW];   // 36000 B
    __shared__ int   cnt[NCLS];          //  4000 B
    __shared__ float red[TPB / 64];

    const int bid   = blockIdx.x;
    const int chunk = bid & (CHUNKS - 1);   // same-chunk blocks land on same XCD
    const int g     = bid >> 6;             // dim group 0..7
    const int tid   = threadIdx.x;
    const bool do_cnt = (g == 0);

    for (int i = tid; i < NCLS * ACCW; i += TPB) acc[i] = 0.f;
    if (do_cnt) for (int i = tid; i < NCLS; i += TPB) cnt[i] = 0;
    __syncthreads();

    const int rows_per_chunk = (n + CHUNKS - 1) / CHUNKS;
    const int r0 = chunk * rows_per_chunk;
    const int r1 = min(n, r0 + rows_per_chunk);
    const int coff = g * DSUB;

    float ssq = 0.f;
    for (int rb = r0; rb < r1; rb += 2 * TPB) {
        const int ra = rb + tid;
        const int rc = ra + TPB;
        const bool p0 = ra < r1;
        const bool p1 = rc < r1;
        int t0 = 0, t1 = 0;
        float4 v0a = make_float4(0.f,0.f,0.f,0.f), v0b = make_float4(0.f,0.f,0.f,0.f);
        float4 v1a = make_float4(0.f,0.f,0.f,0.f), v1b = make_float4(0.f,0.f,0.f,0.f);
        if (p0) {
            t0  = tgt[ra];
            v0a = *reinterpret_cast<const float4*>(emb + (size_t)ra * DIM + coff);
            v0b = *reinterpret_cast<const float4*>(emb + (size_t)ra * DIM + coff + 4);
        }
        if (p1) {
            t1  = tgt[rc];
            v1a = *reinterpret_cast<const float4*>(emb + (size_t)rc * DIM + coff);
            v1b = *reinterpret_cast<const float4*>(emb + (size_t)rc * DIM + coff + 4);
        }
        ssq += v0a.x*v0a.x + v0a.y*v0a.y + v0a.z*v0a.z + v0a.w*v0a.w
             + v0b.x*v0b.x + v0b.y*v0b.y + v0b.z*v0b.z + v0b.w*v0b.w
             + v1a.x*v1a.x + v1a.y*v1a.y + v1a.z*v1a.z + v1a.w*v1a.w
             + v1b.x*v1b.x + v1b.y*v1b.y + v1b.z*v1b.z + v1b.w*v1b.w;
        if (p0) {
            float* a = &acc[t0 * ACCW];
            unsafeAtomicAdd(a + 0, v0a.x); unsafeAtomicAdd(a + 1, v0a.y);
            unsafeAtomicAdd(a + 2, v0a.z); unsafeAtomicAdd(a + 3, v0a.w);
            unsafeAtomicAdd(a + 4, v0b.x); unsafeAtomicAdd(a + 5, v0b.y);
            unsafeAtomicAdd(a + 6, v0b.z); unsafeAtomicAdd(a + 7, v0b.w);
            if (do_cnt) atomicAdd(&cnt[t0], 1);
        }
        if (p1) {
            float* a = &acc[t1 * ACCW];
            unsafeAtomicAdd(a + 0, v1a.x); unsafeAtomicAdd(a + 1, v1a.y);
            unsafeAtomicAdd(a + 2, v1a.z); unsafeAtomicAdd(a + 3, v1a.w);
            unsafeAtomicAdd(a + 4, v1b.x); unsafeAtomicAdd(a + 5, v1b.y);
            unsafeAtomicAdd(a + 6, v1b.z); unsafeAtomicAdd(a + 7, v1b.w);
            if (do_cnt) atomicAdd(&cnt[t1], 1);
        }
    }
    __syncthreads();

    // flush partial sums to global (skip pad lane)
    for (int i = tid; i < NCLS * ACCW; i += TPB) {
        const int c = i / ACCW, d = i - c * ACCW;
        if (d < DSUB) {
            float vsum = acc[i];
            if (vsum != 0.f) unsafeAtomicAdd(&ws->sums[c * DIM + coff + d], vsum);
        }
    }
    if (do_cnt) {
        for (int i = tid; i < NCLS; i += TPB) {
            int c = cnt[i];
            if (c) atomicAdd(&ws->counts[i], c);
        }
    }

    // block-reduce sum of squares -> one double atomic per block
    for (int off = 32; off; off >>= 1) ssq += __shfl_down(ssq, off);
    if ((tid & 63) == 0) red[tid >> 6] = ssq;
    __syncthreads();
    if (tid == 0) {
        float s = 0.f;
        #pragma unroll
        for (int w = 0; w < TPB / 64; ++w) s += red[w];
        atomicAdd(&ws->sumsq, (double)s);
    }
}

// mu = sums / max(counts,1); sq[c] = ||mu_c||^2; muterm += counts_c * sq[c]
// block 0 thread 0 also initializes minkey (saves a launch).
__global__ __launch_bounds__(64) void k_centers(Ws* ws) {
    const int c = blockIdx.x;
    const int d = threadIdx.x;
    if (c == 0 && d == 0) ws->minkey = fkey(1.0e24f);  // matches reference BIG fill
    const int cv = ws->counts[c];
    const float m = ws->sums[c * DIM + d] / (float)max(cv, 1);
    ws->mu[c * DIM + d] = m;
    float p = m * m;
    for (int off = 32; off; off >>= 1) p += __shfl_down(p, off);
    if (d == 0) {
        ws->sq[c] = p;
        if (cv) atomicAdd(&ws->muterm, (double)((float)cv * p));
    }
}

// Tiled pairwise-min: 16x16 upper-triangular 64x64 tiles, 4x4 micro-tile/thread.
#define TILE 64
#define NTA 16                       // ceil(1000/64)
#define NPAIR (NTA * (NTA + 1) / 2)  // 136
__global__ __launch_bounds__(256) void k_pairs(Ws* ws) {
    __shared__ float As[TILE][DIM + 4];   // +4: 16B-aligned, 2-way max on reads
    __shared__ float Bst[DIM][TILE + 1];  // transposed B, 2-way max
    __shared__ float sqa_s[TILE], sqb_s[TILE];
    __shared__ int   pa_s[TILE], pb_s[TILE];
    __shared__ unsigned redm[4];

    // decode upper-triangle tile pair (ta <= tb)
    int rem = blockIdx.x, ta = 0;
    while (rem >= NTA - ta) { rem -= NTA - ta; ++ta; }
    const int tb = ta + rem;
    const int tid = threadIdx.x;

    for (int i = tid; i < TILE * (DIM / 4); i += 256) {
        const int r = i >> 4, c4 = (i & 15) * 4;
        const int ga = ta * TILE + r;
        const int gb = tb * TILE + r;
        float4 va = make_float4(0.f, 0.f, 0.f, 0.f);
        float4 vb = make_float4(0.f, 0.f, 0.f, 0.f);
        if (ga < NCLS) va = *reinterpret_cast<const float4*>(&ws->mu[ga * DIM + c4]);
        if (gb < NCLS) vb = *reinterpret_cast<const float4*>(&ws->mu[gb * DIM + c4]);
        *reinterpret_cast<float4*>(&As[r][c4]) = va;
        Bst[c4 + 0][r] = vb.x; Bst[c4 + 1][r] = vb.y;
        Bst[c4 + 2][r] = vb.z; Bst[c4 + 3][r] = vb.w;
    }
    if (tid < TILE) {
        const int ga = ta * TILE + tid;
        const int gb = tb * TILE + tid;
        pa_s[tid]  = (ga < NCLS) ? (ws->counts[ga] > 0) : 0;
        sqa_s[tid] = (ga < NCLS) ? ws->sq[ga] : 0.f;
        pb_s[tid]  = (gb < NCLS) ? (ws->counts[gb] > 0) : 0;
        sqb_s[tid] = (gb < NCLS) ? ws->sq[gb] : 0.f;
    }
    __syncthreads();

    const int ty4 = (tid >> 4) * 4;
    const int tx4 = (tid & 15) * 4;
    float dot[4][4];
    #pragma unroll
    for (int i = 0; i < 4; ++i)
        #pragma unroll
        for (int j = 0; j < 4; ++j) dot[i][j] = 0.f;

    #pragma unroll 8
    for (int k = 0; k < DIM; ++k) {
        float av[4], bv[4];
        #pragma unroll
        for (int i = 0; i < 4; ++i) av[i] = As[ty4 + i][k];
        #pragma unroll
        for (int j = 0; j < 4; ++j) bv[j] = Bst[k][tx4 + j];
        #pragma unroll
        for (int i = 0; i < 4; ++i)
            #pragma unroll
            for (int j = 0; j < 4; ++j) dot[i][j] += av[i] * bv[j];
    }

    float best = 3.0e38f;
    #pragma unroll
    for (int i = 0; i < 4; ++i) {
        #pragma unroll
        for (int j = 0; j < 4; ++j) {
            const int ga = ta * TILE + ty4 + i;
            const int gb = tb * TILE + tx4 + j;
            const bool valid = pa_s[ty4 + i] && pb_s[tx4 + j] && (ga != gb);
            const float dd = sqa_s[ty4 + i] + sqb_s[tx4 + j] - 2.f * dot[i][j];
            if (valid) best = fminf(best, dd);
        }
    }
    for (int off = 32; off; off >>= 1) best = fminf(best, __shfl_down(best, off));
    if ((tid & 63) == 0) redm[tid >> 6] = fkey(best);
    __syncthreads();
    if (tid == 0) {
        unsigned m = redm[0];
        #pragma unroll
        for (int w = 1; w < 4; ++w) m = min(m, redm[w]);
        atomicMin(&ws->minkey, m);
    }
}

__global__ void k_final(const Ws* ws, float* out, int n) {
    if (threadIdx.x == 0) {
        out[0] = (float)((ws->sumsq - ws->muterm) / (double)n);
        out[1] = -funkey(ws->minkey);
    }
}

extern "C" void kernel_launch(void* const* d_in, const int* in_sizes, int n_in,
                              void* d_out, int out_size, void* d_ws, size_t ws_size,
                              hipStream_t stream) {
    const float* emb = (const float*)d_in[0];
    const int*   tgt = (const int*)d_in[1];
    float* out = (float*)d_out;
    const int n = in_sizes[1];        // 400000 rows
    Ws* ws = (Ws*)d_ws;

    // zero sums/counts/sumsq/muterm; minkey is set inside k_centers
    hipMemsetAsync(d_ws, 0, offsetof(Ws, minkey), stream);
    k_accum<<<DG * CHUNKS, TPB, 0, stream>>>(emb, tgt, n, ws);
    k_centers<<<NCLS, 64, 0, stream>>>(ws);
    k_pairs<<<NPAIR, 256, 0, stream>>>(ws);
    k_final<<<1, 64, 0, stream>>>(ws, out, n);
}

// Round 5
// 153.157 us; speedup vs baseline: 1.1667x; 1.1667x over previous
//
#include <hip/hip_runtime.h>

#define NCLS 1000
#define DIM 64

struct Ws {
    int      counts[NCLS];   // 4000 B (memset region starts here)
    double   sumsq;
    double   muterm;
    unsigned minkey;         // set by k_scan
    unsigned pad_;
    int      offs[NCLS];
    int      cur[NCLS];
    float    mu[NCLS * DIM];
    float    sq[NCLS];
};
// int idxs[n] follows Ws in d_ws.

__device__ __forceinline__ unsigned fkey(float x) {
    unsigned b = __float_as_uint(x);
    return (b & 0x80000000u) ? ~b : (b | 0x80000000u);
}
__device__ __forceinline__ float funkey(unsigned k) {
    return (k & 0x80000000u) ? __uint_as_float(k & 0x7FFFFFFFu)
                             : __uint_as_float(~k);
}

// 1) histogram of target (int LDS atomics -> cheap)
__global__ __launch_bounds__(256) void k_hist(const int* __restrict__ tgt, int n, Ws* ws) {
    __shared__ int h[NCLS];
    for (int i = threadIdx.x; i < NCLS; i += 256) h[i] = 0;
    __syncthreads();
    const int n4 = n >> 2;
    const int4* t4 = reinterpret_cast<const int4*>(tgt);
    for (int i = blockIdx.x * 256 + threadIdx.x; i < n4; i += gridDim.x * 256) {
        const int4 v = t4[i];
        atomicAdd(&h[v.x], 1); atomicAdd(&h[v.y], 1);
        atomicAdd(&h[v.z], 1); atomicAdd(&h[v.w], 1);
    }
    if (blockIdx.x == 0)
        for (int r = (n4 << 2) + threadIdx.x; r < n; r += 256) atomicAdd(&h[tgt[r]], 1);
    __syncthreads();
    for (int i = threadIdx.x; i < NCLS; i += 256) {
        const int c = h[i];
        if (c) atomicAdd(&ws->counts[i], c);
    }
}

// 2) exclusive prefix sum over counts -> offs, cur; init minkey
__global__ __launch_bounds__(1024) void k_scan(Ws* ws) {
    __shared__ int s[1024];
    const int t = threadIdx.x;
    const int myc = (t < NCLS) ? ws->counts[t] : 0;
    s[t] = myc;
    __syncthreads();
    for (int st = 1; st < 1024; st <<= 1) {
        const int v = (t >= st) ? s[t - st] : 0;
        __syncthreads();
        s[t] += v;
        __syncthreads();
    }
    if (t < NCLS) {
        const int e = s[t] - myc;   // exclusive
        ws->offs[t] = e;
        ws->cur[t]  = e;
    }
    if (t == 0) ws->minkey = fkey(1.0e24f);  // matches reference BIG fill
}

// 3) bucket row indices by class (one global int atomic per ROW)
__global__ __launch_bounds__(256) void k_scatter(const int* __restrict__ tgt, int n,
                                                 Ws* ws, int* __restrict__ idxs) {
    for (int r = blockIdx.x * 256 + threadIdx.x; r < n; r += gridDim.x * 256) {
        const int p = atomicAdd(&ws->cur[tgt[r]], 1);
        idxs[p] = r;
    }
}

// 4) per-class register-accumulated reduction; writes mu, sq; sumsq/muterm via
//    one double atomic per block. No float atomics anywhere.
__global__ __launch_bounds__(256) void k_reduce(const float* __restrict__ emb,
                                                const int* __restrict__ idxs, Ws* ws) {
    __shared__ float lds[16][DIM + 4];
    __shared__ float ssq_red[4];
    const int c    = blockIdx.x;
    const int t    = threadIdx.x;
    const int slot = t & 15;     // dim slot: 4 floats
    const int g    = t >> 4;     // row group 0..15
    const int cnt  = ws->counts[c];
    const int off  = ws->offs[c];

    float ax = 0.f, ay = 0.f, az = 0.f, aw = 0.f;
    float ssq = 0.f;
    int i = g;
    for (; i + 16 < cnt; i += 32) {
        const int r0 = idxs[off + i];
        const int r1 = idxs[off + i + 16];
        const float4 v0 = *reinterpret_cast<const float4*>(emb + (size_t)r0 * DIM + slot * 4);
        const float4 v1 = *reinterpret_cast<const float4*>(emb + (size_t)r1 * DIM + slot * 4);
        ax += v0.x; ay += v0.y; az += v0.z; aw += v0.w;
        ax += v1.x; ay += v1.y; az += v1.z; aw += v1.w;
        ssq += v0.x * v0.x + v0.y * v0.y + v0.z * v0.z + v0.w * v0.w
             + v1.x * v1.x + v1.y * v1.y + v1.z * v1.z + v1.w * v1.w;
    }
    if (i < cnt) {
        const int r0 = idxs[off + i];
        const float4 v0 = *reinterpret_cast<const float4*>(emb + (size_t)r0 * DIM + slot * 4);
        ax += v0.x; ay += v0.y; az += v0.z; aw += v0.w;
        ssq += v0.x * v0.x + v0.y * v0.y + v0.z * v0.z + v0.w * v0.w;
    }
    lds[g][slot * 4 + 0] = ax; lds[g][slot * 4 + 1] = ay;
    lds[g][slot * 4 + 2] = az; lds[g][slot * 4 + 3] = aw;
    __syncthreads();
    // tree reduce over row groups
    for (int s = 8; s >= 1; s >>= 1) {
        if (g < s) {
            #pragma unroll
            for (int k = 0; k < 4; ++k)
                lds[g][slot * 4 + k] += lds[g + s][slot * 4 + k];
        }
        __syncthreads();
    }
    // sum-of-squares block reduction
    for (int o = 32; o; o >>= 1) ssq += __shfl_down(ssq, o);
    if ((t & 63) == 0) ssq_red[t >> 6] = ssq;
    __syncthreads();

    if (t < DIM) {  // wave 0
        const float m = lds[0][t] / (float)max(cnt, 1);
        ws->mu[c * DIM + t] = m;
        float p = m * m;
        for (int o = 32; o; o >>= 1) p += __shfl_down(p, o);
        if (t == 0) {
            ws->sq[c] = p;
            if (cnt) atomicAdd(&ws->muterm, (double)((float)cnt * p));
            const float s2 = ssq_red[0] + ssq_red[1] + ssq_red[2] + ssq_red[3];
            atomicAdd(&ws->sumsq, (double)s2);
        }
    }
}

// 5) tiled pairwise-min over centers: 64x64 upper-triangular tiles, 4x4 micro-tile
#define TILE 64
#define NTA 16
#define NPAIR (NTA * (NTA + 1) / 2)  // 136
__global__ __launch_bounds__(256) void k_pairs(Ws* ws) {
    __shared__ float As[TILE][DIM + 4];
    __shared__ float Bst[DIM][TILE + 1];
    __shared__ float sqa_s[TILE], sqb_s[TILE];
    __shared__ int   pa_s[TILE], pb_s[TILE];
    __shared__ unsigned redm[4];

    int rem = blockIdx.x, ta = 0;
    while (rem >= NTA - ta) { rem -= NTA - ta; ++ta; }
    const int tb = ta + rem;
    const int tid = threadIdx.x;

    for (int i = tid; i < TILE * (DIM / 4); i += 256) {
        const int r = i >> 4, c4 = (i & 15) * 4;
        const int ga = ta * TILE + r;
        const int gb = tb * TILE + r;
        float4 va = make_float4(0.f, 0.f, 0.f, 0.f);
        float4 vb = make_float4(0.f, 0.f, 0.f, 0.f);
        if (ga < NCLS) va = *reinterpret_cast<const float4*>(&ws->mu[ga * DIM + c4]);
        if (gb < NCLS) vb = *reinterpret_cast<const float4*>(&ws->mu[gb * DIM + c4]);
        *reinterpret_cast<float4*>(&As[r][c4]) = va;
        Bst[c4 + 0][r] = vb.x; Bst[c4 + 1][r] = vb.y;
        Bst[c4 + 2][r] = vb.z; Bst[c4 + 3][r] = vb.w;
    }
    if (tid < TILE) {
        const int ga = ta * TILE + tid;
        const int gb = tb * TILE + tid;
        pa_s[tid]  = (ga < NCLS) ? (ws->counts[ga] > 0) : 0;
        sqa_s[tid] = (ga < NCLS) ? ws->sq[ga] : 0.f;
        pb_s[tid]  = (gb < NCLS) ? (ws->counts[gb] > 0) : 0;
        sqb_s[tid] = (gb < NCLS) ? ws->sq[gb] : 0.f;
    }
    __syncthreads();

    const int ty4 = (tid >> 4) * 4;
    const int tx4 = (tid & 15) * 4;
    float dot[4][4];
    #pragma unroll
    for (int i = 0; i < 4; ++i)
        #pragma unroll
        for (int j = 0; j < 4; ++j) dot[i][j] = 0.f;

    #pragma unroll 8
    for (int k = 0; k < DIM; ++k) {
        float av[4], bv[4];
        #pragma unroll
        for (int i = 0; i < 4; ++i) av[i] = As[ty4 + i][k];
        #pragma unroll
        for (int j = 0; j < 4; ++j) bv[j] = Bst[k][tx4 + j];
        #pragma unroll
        for (int i = 0; i < 4; ++i)
            #pragma unroll
            for (int j = 0; j < 4; ++j) dot[i][j] += av[i] * bv[j];
    }

    float best = 3.0e38f;
    #pragma unroll
    for (int i = 0; i < 4; ++i) {
        #pragma unroll
        for (int j = 0; j < 4; ++j) {
            const int ga = ta * TILE + ty4 + i;
            const int gb = tb * TILE + tx4 + j;
            const bool valid = pa_s[ty4 + i] && pb_s[tx4 + j] && (ga != gb);
            const float dd = sqa_s[ty4 + i] + sqb_s[tx4 + j] - 2.f * dot[i][j];
            if (valid) best = fminf(best, dd);
        }
    }
    for (int off = 32; off; off >>= 1) best = fminf(best, __shfl_down(best, off));
    if ((tid & 63) == 0) redm[tid >> 6] = fkey(best);
    __syncthreads();
    if (tid == 0) {
        unsigned m = redm[0];
        #pragma unroll
        for (int w = 1; w < 4; ++w) m = min(m, redm[w]);
        atomicMin(&ws->minkey, m);
    }
}

__global__ void k_final(const Ws* ws, float* out, int n) {
    if (threadIdx.x == 0) {
        out[0] = (float)((ws->sumsq - ws->muterm) / (double)n);
        out[1] = -funkey(ws->minkey);
    }
}

extern "C" void kernel_launch(void* const* d_in, const int* in_sizes, int n_in,
                              void* d_out, int out_size, void* d_ws, size_t ws_size,
                              hipStream_t stream) {
    const float* emb = (const float*)d_in[0];
    const int*   tgt = (const int*)d_in[1];
    float* out = (float*)d_out;
    const int n = in_sizes[1];        // 400000 rows
    Ws* ws = (Ws*)d_ws;
    int* idxs = (int*)((char*)d_ws + sizeof(Ws));

    hipMemsetAsync(d_ws, 0, offsetof(Ws, minkey), stream);  // counts+sumsq+muterm
    k_hist   <<<256, 256, 0, stream>>>(tgt, n, ws);
    k_scan   <<<1, 1024, 0, stream>>>(ws);
    k_scatter<<<1024, 256, 0, stream>>>(tgt, n, ws, idxs);
    k_reduce <<<NCLS, 256, 0, stream>>>(emb, idxs, ws);
    k_pairs  <<<NPAIR, 256, 0, stream>>>(ws);
    k_final  <<<1, 64, 0, stream>>>(ws, out, n);
}

// Round 6
// 89.355 us; speedup vs baseline: 1.9998x; 1.7140x over previous
//
#include <hip/hip_runtime.h>

#define NCLS 1000
#define DIM 64
#define CURW 32   // cursor stride in ints: one cursor per 128B cache line

struct Ws {
    int      counts[NCLS];   // 4000 B (memset region starts here)
    double   sumsq;
    double   muterm;
    unsigned minkey;         // set by k_scan
    unsigned pad_;
    int      offs[NCLS];
    float    mu[NCLS * DIM];
    float    sq[NCLS];
    int      cur[NCLS * CURW];  // line-padded cursors (128 KB)
};
// int idxs[n] follows Ws in d_ws.

__device__ __forceinline__ unsigned fkey(float x) {
    unsigned b = __float_as_uint(x);
    return (b & 0x80000000u) ? ~b : (b | 0x80000000u);
}
__device__ __forceinline__ float funkey(unsigned k) {
    return (k & 0x80000000u) ? __uint_as_float(k & 0x7FFFFFFFu)
                             : __uint_as_float(~k);
}

// 1) histogram of target (int LDS atomics -> cheap)
__global__ __launch_bounds__(256) void k_hist(const int* __restrict__ tgt, int n, Ws* ws) {
    __shared__ int h[NCLS];
    for (int i = threadIdx.x; i < NCLS; i += 256) h[i] = 0;
    __syncthreads();
    const int n4 = n >> 2;
    const int4* t4 = reinterpret_cast<const int4*>(tgt);
    for (int i = blockIdx.x * 256 + threadIdx.x; i < n4; i += gridDim.x * 256) {
        const int4 v = t4[i];
        atomicAdd(&h[v.x], 1); atomicAdd(&h[v.y], 1);
        atomicAdd(&h[v.z], 1); atomicAdd(&h[v.w], 1);
    }
    if (blockIdx.x == 0)
        for (int r = (n4 << 2) + threadIdx.x; r < n; r += 256) atomicAdd(&h[tgt[r]], 1);
    __syncthreads();
    for (int i = threadIdx.x; i < NCLS; i += 256) {
        const int c = h[i];
        if (c) atomicAdd(&ws->counts[i], c);
    }
}

// 2) exclusive prefix sum over counts -> offs, padded cur; init minkey
__global__ __launch_bounds__(1024) void k_scan(Ws* ws) {
    __shared__ int s[1024];
    const int t = threadIdx.x;
    const int myc = (t < NCLS) ? ws->counts[t] : 0;
    s[t] = myc;
    __syncthreads();
    for (int st = 1; st < 1024; st <<= 1) {
        const int v = (t >= st) ? s[t - st] : 0;
        __syncthreads();
        s[t] += v;
        __syncthreads();
    }
    if (t < NCLS) {
        const int e = s[t] - myc;   // exclusive
        ws->offs[t] = e;
        ws->cur[t * CURW] = e;
    }
    if (t == 0) ws->minkey = fkey(1.0e24f);  // matches reference BIG fill
}

// 3) bucket row indices by class (one global int atomic per ROW, line-padded cursors)
__global__ __launch_bounds__(256) void k_scatter(const int* __restrict__ tgt, int n,
                                                 Ws* ws, int* __restrict__ idxs) {
    for (int r = blockIdx.x * 256 + threadIdx.x; r < n; r += gridDim.x * 256) {
        const int p = atomicAdd(&ws->cur[tgt[r] * CURW], 1);
        idxs[p] = r;
    }
}

// 4) per-class register-accumulated reduction; writes mu, sq; sumsq/muterm via
//    one double atomic per block. No float atomics anywhere.
__global__ __launch_bounds__(256) void k_reduce(const float* __restrict__ emb,
                                                const int* __restrict__ idxs, Ws* ws) {
    __shared__ float lds[16][DIM + 4];
    __shared__ float ssq_red[4];
    const int c    = blockIdx.x;
    const int t    = threadIdx.x;
    const int slot = t & 15;     // dim slot: 4 floats
    const int g    = t >> 4;     // row group 0..15
    const int cnt  = ws->counts[c];
    const int off  = ws->offs[c];

    float ax = 0.f, ay = 0.f, az = 0.f, aw = 0.f;
    float ssq = 0.f;
    int i = g;
    for (; i + 16 < cnt; i += 32) {
        const int r0 = idxs[off + i];
        const int r1 = idxs[off + i + 16];
        const float4 v0 = *reinterpret_cast<const float4*>(emb + (size_t)r0 * DIM + slot * 4);
        const float4 v1 = *reinterpret_cast<const float4*>(emb + (size_t)r1 * DIM + slot * 4);
        ax += v0.x; ay += v0.y; az += v0.z; aw += v0.w;
        ax += v1.x; ay += v1.y; az += v1.z; aw += v1.w;
        ssq += v0.x * v0.x + v0.y * v0.y + v0.z * v0.z + v0.w * v0.w
             + v1.x * v1.x + v1.y * v1.y + v1.z * v1.z + v1.w * v1.w;
    }
    if (i < cnt) {
        const int r0 = idxs[off + i];
        const float4 v0 = *reinterpret_cast<const float4*>(emb + (size_t)r0 * DIM + slot * 4);
        ax += v0.x; ay += v0.y; az += v0.z; aw += v0.w;
        ssq += v0.x * v0.x + v0.y * v0.y + v0.z * v0.z + v0.w * v0.w;
    }
    lds[g][slot * 4 + 0] = ax; lds[g][slot * 4 + 1] = ay;
    lds[g][slot * 4 + 2] = az; lds[g][slot * 4 + 3] = aw;
    __syncthreads();
    // tree reduce over row groups
    for (int s = 8; s >= 1; s >>= 1) {
        if (g < s) {
            #pragma unroll
            for (int k = 0; k < 4; ++k)
                lds[g][slot * 4 + k] += lds[g + s][slot * 4 + k];
        }
        __syncthreads();
    }
    // sum-of-squares block reduction
    for (int o = 32; o; o >>= 1) ssq += __shfl_down(ssq, o);
    if ((t & 63) == 0) ssq_red[t >> 6] = ssq;
    __syncthreads();

    if (t < DIM) {  // wave 0
        const float m = lds[0][t] / (float)max(cnt, 1);
        ws->mu[c * DIM + t] = m;
        float p = m * m;
        for (int o = 32; o; o >>= 1) p += __shfl_down(p, o);
        if (t == 0) {
            ws->sq[c] = p;
            if (cnt) atomicAdd(&ws->muterm, (double)((float)cnt * p));
            const float s2 = ssq_red[0] + ssq_red[1] + ssq_red[2] + ssq_red[3];
            atomicAdd(&ws->sumsq, (double)s2);
        }
    }
}

// 5) tiled pairwise-min over centers: 64x64 upper-triangular tiles, 4x4 micro-tile
#define TILE 64
#define NTA 16
#define NPAIR (NTA * (NTA + 1) / 2)  // 136
__global__ __launch_bounds__(256) void k_pairs(Ws* ws) {
    __shared__ float As[TILE][DIM + 4];
    __shared__ float Bst[DIM][TILE + 1];
    __shared__ float sqa_s[TILE], sqb_s[TILE];
    __shared__ int   pa_s[TILE], pb_s[TILE];
    __shared__ unsigned redm[4];

    int rem = blockIdx.x, ta = 0;
    while (rem >= NTA - ta) { rem -= NTA - ta; ++ta; }
    const int tb = ta + rem;
    const int tid = threadIdx.x;

    for (int i = tid; i < TILE * (DIM / 4); i += 256) {
        const int r = i >> 4, c4 = (i & 15) * 4;
        const int ga = ta * TILE + r;
        const int gb = tb * TILE + r;
        float4 va = make_float4(0.f, 0.f, 0.f, 0.f);
        float4 vb = make_float4(0.f, 0.f, 0.f, 0.f);
        if (ga < NCLS) va = *reinterpret_cast<const float4*>(&ws->mu[ga * DIM + c4]);
        if (gb < NCLS) vb = *reinterpret_cast<const float4*>(&ws->mu[gb * DIM + c4]);
        *reinterpret_cast<float4*>(&As[r][c4]) = va;
        Bst[c4 + 0][r] = vb.x; Bst[c4 + 1][r] = vb.y;
        Bst[c4 + 2][r] = vb.z; Bst[c4 + 3][r] = vb.w;
    }
    if (tid < TILE) {
        const int ga = ta * TILE + tid;
        const int gb = tb * TILE + tid;
        pa_s[tid]  = (ga < NCLS) ? (ws->counts[ga] > 0) : 0;
        sqa_s[tid] = (ga < NCLS) ? ws->sq[ga] : 0.f;
        pb_s[tid]  = (gb < NCLS) ? (ws->counts[gb] > 0) : 0;
        sqb_s[tid] = (gb < NCLS) ? ws->sq[gb] : 0.f;
    }
    __syncthreads();

    const int ty4 = (tid >> 4) * 4;
    const int tx4 = (tid & 15) * 4;
    float dot[4][4];
    #pragma unroll
    for (int i = 0; i < 4; ++i)
        #pragma unroll
        for (int j = 0; j < 4; ++j) dot[i][j] = 0.f;

    #pragma unroll 8
    for (int k = 0; k < DIM; ++k) {
        float av[4], bv[4];
        #pragma unroll
        for (int i = 0; i < 4; ++i) av[i] = As[ty4 + i][k];
        #pragma unroll
        for (int j = 0; j < 4; ++j) bv[j] = Bst[k][tx4 + j];
        #pragma unroll
        for (int i = 0; i < 4; ++i)
            #pragma unroll
            for (int j = 0; j < 4; ++j) dot[i][j] += av[i] * bv[j];
    }

    float best = 3.0e38f;
    #pragma unroll
    for (int i = 0; i < 4; ++i) {
        #pragma unroll
        for (int j = 0; j < 4; ++j) {
            const int ga = ta * TILE + ty4 + i;
            const int gb = tb * TILE + tx4 + j;
            const bool valid = pa_s[ty4 + i] && pb_s[tx4 + j] && (ga != gb);
            const float dd = sqa_s[ty4 + i] + sqb_s[tx4 + j] - 2.f * dot[i][j];
            if (valid) best = fminf(best, dd);
        }
    }
    for (int off = 32; off; off >>= 1) best = fminf(best, __shfl_down(best, off));
    if ((tid & 63) == 0) redm[tid >> 6] = fkey(best);
    __syncthreads();
    if (tid == 0) {
        unsigned m = redm[0];
        #pragma unroll
        for (int w = 1; w < 4; ++w) m = min(m, redm[w]);
        atomicMin(&ws->minkey, m);
    }
}

__global__ void k_final(const Ws* ws, float* out, int n) {
    if (threadIdx.x == 0) {
        out[0] = (float)((ws->sumsq - ws->muterm) / (double)n);
        out[1] = -funkey(ws->minkey);
    }
}

extern "C" void kernel_launch(void* const* d_in, const int* in_sizes, int n_in,
                              void* d_out, int out_size, void* d_ws, size_t ws_size,
                              hipStream_t stream) {
    const float* emb = (const float*)d_in[0];
    const int*   tgt = (const int*)d_in[1];
    float* out = (float*)d_out;
    const int n = in_sizes[1];        // 400000 rows
    Ws* ws = (Ws*)d_ws;
    int* idxs = (int*)((char*)d_ws + sizeof(Ws));

    hipMemsetAsync(d_ws, 0, offsetof(Ws, minkey), stream);  // counts+sumsq+muterm
    k_hist   <<<256, 256, 0, stream>>>(tgt, n, ws);
    k_scan   <<<1, 1024, 0, stream>>>(ws);
    k_scatter<<<1024, 256, 0, stream>>>(tgt, n, ws, idxs);
    k_reduce <<<NCLS, 256, 0, stream>>>(emb, idxs, ws);
    k_pairs  <<<NPAIR, 256, 0, stream>>>(ws);
    k_final  <<<1, 64, 0, stream>>>(ws, out, n);
}

// Round 7
// 72.184 us; speedup vs baseline: 2.4754x; 1.2379x over previous
//
#include <hip/hip_runtime.h>

#define NCLS 1000
#define DIM 64
#define CURW 32   // cursor stride in ints: one cursor per 128B cache line
#define SPLIT 4   // reduce-blocks per class

struct Ws {
    int      counts[NCLS];      // 4000 B (memset region = this only)
    unsigned minkey;            // set by k_scan
    unsigned pad_;
    int      offs[NCLS];
    float    mu[NCLS * DIM];
    float    sq[NCLS];
    int      cur[NCLS * CURW];  // line-padded cursors (128 KB)
};
// layout after Ws in d_ws:
//   int   idxs[n]
//   float part[NCLS*SPLIT*DIM]
//   float part_ssq[NCLS*SPLIT]
//   float cls_ssq[NCLS]
//   float cls_mt[NCLS]

__device__ __forceinline__ unsigned fkey(float x) {
    unsigned b = __float_as_uint(x);
    return (b & 0x80000000u) ? ~b : (b | 0x80000000u);
}
__device__ __forceinline__ float funkey(unsigned k) {
    return (k & 0x80000000u) ? __uint_as_float(k & 0x7FFFFFFFu)
                             : __uint_as_float(~k);
}

// 1) histogram of target (int LDS atomics -> cheap)
__global__ __launch_bounds__(256) void k_hist(const int* __restrict__ tgt, int n, Ws* ws) {
    __shared__ int h[NCLS];
    for (int i = threadIdx.x; i < NCLS; i += 256) h[i] = 0;
    __syncthreads();
    const int n4 = n >> 2;
    const int4* t4 = reinterpret_cast<const int4*>(tgt);
    for (int i = blockIdx.x * 256 + threadIdx.x; i < n4; i += gridDim.x * 256) {
        const int4 v = t4[i];
        atomicAdd(&h[v.x], 1); atomicAdd(&h[v.y], 1);
        atomicAdd(&h[v.z], 1); atomicAdd(&h[v.w], 1);
    }
    if (blockIdx.x == 0)
        for (int r = (n4 << 2) + threadIdx.x; r < n; r += 256) atomicAdd(&h[tgt[r]], 1);
    __syncthreads();
    for (int i = threadIdx.x; i < NCLS; i += 256) {
        const int c = h[i];
        if (c) atomicAdd(&ws->counts[i], c);
    }
}

// 2) exclusive prefix sum over counts -> offs, padded cur; init minkey
__global__ __launch_bounds__(1024) void k_scan(Ws* ws) {
    __shared__ int s[1024];
    const int t = threadIdx.x;
    const int myc = (t < NCLS) ? ws->counts[t] : 0;
    s[t] = myc;
    __syncthreads();
    for (int st = 1; st < 1024; st <<= 1) {
        const int v = (t >= st) ? s[t - st] : 0;
        __syncthreads();
        s[t] += v;
        __syncthreads();
    }
    if (t < NCLS) {
        const int e = s[t] - myc;   // exclusive
        ws->offs[t] = e;
        ws->cur[t * CURW] = e;
    }
    if (t == 0) ws->minkey = fkey(1.0e24f);  // matches reference BIG fill
}

// 3) bucket row indices by class (one global int atomic per ROW, line-padded cursors)
__global__ __launch_bounds__(256) void k_scatter(const int* __restrict__ tgt, int n,
                                                 Ws* ws, int* __restrict__ idxs) {
    for (int r = blockIdx.x * 256 + threadIdx.x; r < n; r += gridDim.x * 256) {
        const int p = atomicAdd(&ws->cur[tgt[r] * CURW], 1);
        idxs[p] = r;
    }
}

// 4) per-(class,split) register-accumulated partial reduction; plain stores only.
__global__ __launch_bounds__(256) void k_reduce(const float* __restrict__ emb,
                                                const int* __restrict__ idxs,
                                                const Ws* __restrict__ ws,
                                                float* __restrict__ part,
                                                float* __restrict__ part_ssq) {
    __shared__ float lds[16][DIM + 4];
    __shared__ float ssq_red[4];
    const int bid  = blockIdx.x;
    const int c    = bid >> 2;          // class
    const int sp   = bid & (SPLIT - 1); // split slice
    const int t    = threadIdx.x;
    const int slot = t & 15;            // dim slot: 4 floats
    const int g    = t >> 4;            // row group 0..15
    const int cnt  = ws->counts[c];
    const int i0   = (cnt * sp) / SPLIT;
    const int i1   = (cnt * (sp + 1)) / SPLIT;
    const int base = ws->offs[c] + i0;
    const int m    = i1 - i0;

    float ax = 0.f, ay = 0.f, az = 0.f, aw = 0.f;
    float ssq = 0.f;
    int i = g;
    for (; i + 16 < m; i += 32) {
        const int r0 = idxs[base + i];
        const int r1 = idxs[base + i + 16];
        const float4 v0 = *reinterpret_cast<const float4*>(emb + (size_t)r0 * DIM + slot * 4);
        const float4 v1 = *reinterpret_cast<const float4*>(emb + (size_t)r1 * DIM + slot * 4);
        ax += v0.x; ay += v0.y; az += v0.z; aw += v0.w;
        ax += v1.x; ay += v1.y; az += v1.z; aw += v1.w;
        ssq += v0.x * v0.x + v0.y * v0.y + v0.z * v0.z + v0.w * v0.w
             + v1.x * v1.x + v1.y * v1.y + v1.z * v1.z + v1.w * v1.w;
    }
    if (i < m) {
        const int r0 = idxs[base + i];
        const float4 v0 = *reinterpret_cast<const float4*>(emb + (size_t)r0 * DIM + slot * 4);
        ax += v0.x; ay += v0.y; az += v0.z; aw += v0.w;
        ssq += v0.x * v0.x + v0.y * v0.y + v0.z * v0.z + v0.w * v0.w;
    }
    lds[g][slot * 4 + 0] = ax; lds[g][slot * 4 + 1] = ay;
    lds[g][slot * 4 + 2] = az; lds[g][slot * 4 + 3] = aw;
    __syncthreads();
    for (int s = 8; s >= 1; s >>= 1) {
        if (g < s) {
            #pragma unroll
            for (int k = 0; k < 4; ++k)
                lds[g][slot * 4 + k] += lds[g + s][slot * 4 + k];
        }
        __syncthreads();
    }
    for (int o = 32; o; o >>= 1) ssq += __shfl_down(ssq, o);
    if ((t & 63) == 0) ssq_red[t >> 6] = ssq;
    __syncthreads();
    if (t < DIM) part[bid * DIM + t] = lds[0][t];
    if (t == 0)
        part_ssq[bid] = ssq_red[0] + ssq_red[1] + ssq_red[2] + ssq_red[3];
}

// 4b) combine SPLIT partials -> mu, sq, per-class ssq and count*||mu||^2 terms
__global__ __launch_bounds__(64) void k_centers(Ws* ws,
                                                const float* __restrict__ part,
                                                const float* __restrict__ part_ssq,
                                                float* __restrict__ cls_ssq,
                                                float* __restrict__ cls_mt) {
    const int c = blockIdx.x;
    const int t = threadIdx.x;
    const int cnt = ws->counts[c];
    float v = 0.f;
    #pragma unroll
    for (int s = 0; s < SPLIT; ++s) v += part[(c * SPLIT + s) * DIM + t];
    const float m = v / (float)max(cnt, 1);
    ws->mu[c * DIM + t] = m;
    float p = m * m;
    for (int o = 32; o; o >>= 1) p += __shfl_down(p, o);
    if (t == 0) {
        ws->sq[c] = p;
        cls_mt[c] = cnt ? (float)cnt * p : 0.f;
        float s2 = 0.f;
        #pragma unroll
        for (int s = 0; s < SPLIT; ++s) s2 += part_ssq[c * SPLIT + s];
        cls_ssq[c] = s2;
    }
}

// 5) tiled pairwise-min over centers: 64x64 upper-triangular tiles, 4x4 micro-tile
#define TILE 64
#define NTA 16
#define NPAIR (NTA * (NTA + 1) / 2)  // 136
__global__ __launch_bounds__(256) void k_pairs(Ws* ws) {
    __shared__ float As[TILE][DIM + 4];
    __shared__ float Bst[DIM][TILE + 1];
    __shared__ float sqa_s[TILE], sqb_s[TILE];
    __shared__ int   pa_s[TILE], pb_s[TILE];
    __shared__ unsigned redm[4];

    int rem = blockIdx.x, ta = 0;
    while (rem >= NTA - ta) { rem -= NTA - ta; ++ta; }
    const int tb = ta + rem;
    const int tid = threadIdx.x;

    for (int i = tid; i < TILE * (DIM / 4); i += 256) {
        const int r = i >> 4, c4 = (i & 15) * 4;
        const int ga = ta * TILE + r;
        const int gb = tb * TILE + r;
        float4 va = make_float4(0.f, 0.f, 0.f, 0.f);
        float4 vb = make_float4(0.f, 0.f, 0.f, 0.f);
        if (ga < NCLS) va = *reinterpret_cast<const float4*>(&ws->mu[ga * DIM + c4]);
        if (gb < NCLS) vb = *reinterpret_cast<const float4*>(&ws->mu[gb * DIM + c4]);
        *reinterpret_cast<float4*>(&As[r][c4]) = va;
        Bst[c4 + 0][r] = vb.x; Bst[c4 + 1][r] = vb.y;
        Bst[c4 + 2][r] = vb.z; Bst[c4 + 3][r] = vb.w;
    }
    if (tid < TILE) {
        const int ga = ta * TILE + tid;
        const int gb = tb * TILE + tid;
        pa_s[tid]  = (ga < NCLS) ? (ws->counts[ga] > 0) : 0;
        sqa_s[tid] = (ga < NCLS) ? ws->sq[ga] : 0.f;
        pb_s[tid]  = (gb < NCLS) ? (ws->counts[gb] > 0) : 0;
        sqb_s[tid] = (gb < NCLS) ? ws->sq[gb] : 0.f;
    }
    __syncthreads();

    const int ty4 = (tid >> 4) * 4;
    const int tx4 = (tid & 15) * 4;
    float dot[4][4];
    #pragma unroll
    for (int i = 0; i < 4; ++i)
        #pragma unroll
        for (int j = 0; j < 4; ++j) dot[i][j] = 0.f;

    #pragma unroll 8
    for (int k = 0; k < DIM; ++k) {
        float av[4], bv[4];
        #pragma unroll
        for (int i = 0; i < 4; ++i) av[i] = As[ty4 + i][k];
        #pragma unroll
        for (int j = 0; j < 4; ++j) bv[j] = Bst[k][tx4 + j];
        #pragma unroll
        for (int i = 0; i < 4; ++i)
            #pragma unroll
            for (int j = 0; j < 4; ++j) dot[i][j] += av[i] * bv[j];
    }

    float best = 3.0e38f;
    #pragma unroll
    for (int i = 0; i < 4; ++i) {
        #pragma unroll
        for (int j = 0; j < 4; ++j) {
            const int ga = ta * TILE + ty4 + i;
            const int gb = tb * TILE + tx4 + j;
            const bool valid = pa_s[ty4 + i] && pb_s[tx4 + j] && (ga != gb);
            const float dd = sqa_s[ty4 + i] + sqb_s[tx4 + j] - 2.f * dot[i][j];
            if (valid) best = fminf(best, dd);
        }
    }
    for (int off = 32; off; off >>= 1) best = fminf(best, __shfl_down(best, off));
    if ((tid & 63) == 0) redm[tid >> 6] = fkey(best);
    __syncthreads();
    if (tid == 0) {
        unsigned m = redm[0];
        #pragma unroll
        for (int w = 1; w < 4; ++w) m = min(m, redm[w]);
        atomicMin(&ws->minkey, m);
    }
}

// 6) final: double-precision reduce of per-class terms + min distance
__global__ __launch_bounds__(256) void k_final(const Ws* ws,
                                               const float* __restrict__ cls_ssq,
                                               const float* __restrict__ cls_mt,
                                               float* out, int n) {
    __shared__ double sd[256], md[256];
    const int t = threadIdx.x;
    double a = 0.0, b = 0.0;
    for (int i = t; i < NCLS; i += 256) { a += (double)cls_ssq[i]; b += (double)cls_mt[i]; }
    sd[t] = a; md[t] = b;
    __syncthreads();
    for (int s = 128; s >= 1; s >>= 1) {
        if (t < s) { sd[t] += sd[t + s]; md[t] += md[t + s]; }
        __syncthreads();
    }
    if (t == 0) {
        out[0] = (float)((sd[0] - md[0]) / (double)n);
        out[1] = -funkey(ws->minkey);
    }
}

extern "C" void kernel_launch(void* const* d_in, const int* in_sizes, int n_in,
                              void* d_out, int out_size, void* d_ws, size_t ws_size,
                              hipStream_t stream) {
    const float* emb = (const float*)d_in[0];
    const int*   tgt = (const int*)d_in[1];
    float* out = (float*)d_out;
    const int n = in_sizes[1];        // 400000 rows
    Ws* ws = (Ws*)d_ws;
    char* p = (char*)d_ws + sizeof(Ws);
    int*   idxs     = (int*)p;                 p += (size_t)n * sizeof(int);
    float* part     = (float*)p;               p += (size_t)NCLS * SPLIT * DIM * sizeof(float);
    float* part_ssq = (float*)p;               p += (size_t)NCLS * SPLIT * sizeof(float);
    float* cls_ssq  = (float*)p;               p += (size_t)NCLS * sizeof(float);
    float* cls_mt   = (float*)p;

    hipMemsetAsync(d_ws, 0, offsetof(Ws, minkey), stream);  // counts only
    k_hist   <<<256, 256, 0, stream>>>(tgt, n, ws);
    k_scan   <<<1, 1024, 0, stream>>>(ws);
    k_scatter<<<1024, 256, 0, stream>>>(tgt, n, ws, idxs);
    k_reduce <<<NCLS * SPLIT, 256, 0, stream>>>(emb, idxs, ws, part, part_ssq);
    k_centers<<<NCLS, 64, 0, stream>>>(ws, part, part_ssq, cls_ssq, cls_mt);
    k_pairs  <<<NPAIR, 256, 0, stream>>>(ws);
    k_final  <<<1, 256, 0, stream>>>(ws, cls_ssq, cls_mt, out, n);
}

// Round 8
// 72.156 us; speedup vs baseline: 2.4764x; 1.0004x over previous
//
#include <hip/hip_runtime.h>

#define NCLS 1000
#define DIM 64
#define CURW 32   // cursor stride in ints: one cursor per 128B cache line
#define SPLIT 4   // reduce-blocks per class
#define STAGE 512 // idx staging chunk (LDS)

struct Ws {
    int      counts[NCLS];      // zeroed by k_zero
    unsigned minkey;            // set by k_scan
    unsigned pad_;
    int      offs[NCLS];
    float    mu[NCLS * DIM];
    float    sq[NCLS];
    int      cur[NCLS * CURW];  // line-padded cursors (128 KB)
};
// layout after Ws in d_ws:
//   int   idxs[n]
//   float part[NCLS*SPLIT*DIM]
//   float part_ssq[NCLS*SPLIT]
//   float cls_ssq[NCLS]
//   float cls_mt[NCLS]

__device__ __forceinline__ unsigned fkey(float x) {
    unsigned b = __float_as_uint(x);
    return (b & 0x80000000u) ? ~b : (b | 0x80000000u);
}
__device__ __forceinline__ float funkey(unsigned k) {
    return (k & 0x80000000u) ? __uint_as_float(k & 0x7FFFFFFFu)
                             : __uint_as_float(~k);
}

// 0) zero counts (replaces hipMemsetAsync fill node in the graph)
__global__ __launch_bounds__(256) void k_zero(Ws* ws) {
    const int t = blockIdx.x * 256 + threadIdx.x;
    if (t < NCLS) ws->counts[t] = 0;
}

// 1) histogram of target (int LDS atomics -> cheap)
__global__ __launch_bounds__(256) void k_hist(const int* __restrict__ tgt, int n, Ws* ws) {
    __shared__ int h[NCLS];
    for (int i = threadIdx.x; i < NCLS; i += 256) h[i] = 0;
    __syncthreads();
    const int n4 = n >> 2;
    const int4* t4 = reinterpret_cast<const int4*>(tgt);
    for (int i = blockIdx.x * 256 + threadIdx.x; i < n4; i += gridDim.x * 256) {
        const int4 v = t4[i];
        atomicAdd(&h[v.x], 1); atomicAdd(&h[v.y], 1);
        atomicAdd(&h[v.z], 1); atomicAdd(&h[v.w], 1);
    }
    if (blockIdx.x == 0)
        for (int r = (n4 << 2) + threadIdx.x; r < n; r += 256) atomicAdd(&h[tgt[r]], 1);
    __syncthreads();
    for (int i = threadIdx.x; i < NCLS; i += 256) {
        const int c = h[i];
        if (c) atomicAdd(&ws->counts[i], c);
    }
}

// 2) exclusive prefix sum over counts -> offs, padded cur; init minkey
__global__ __launch_bounds__(1024) void k_scan(Ws* ws) {
    __shared__ int s[1024];
    const int t = threadIdx.x;
    const int myc = (t < NCLS) ? ws->counts[t] : 0;
    s[t] = myc;
    __syncthreads();
    for (int st = 1; st < 1024; st <<= 1) {
        const int v = (t >= st) ? s[t - st] : 0;
        __syncthreads();
        s[t] += v;
        __syncthreads();
    }
    if (t < NCLS) {
        const int e = s[t] - myc;   // exclusive
        ws->offs[t] = e;
        ws->cur[t * CURW] = e;
    }
    if (t == 0) ws->minkey = fkey(1.0e24f);  // matches reference BIG fill
}

// 3) bucket row indices by class (one global int atomic per ROW, line-padded cursors)
__global__ __launch_bounds__(256) void k_scatter(const int* __restrict__ tgt, int n,
                                                 Ws* ws, int* __restrict__ idxs) {
    for (int r = blockIdx.x * 256 + threadIdx.x; r < n; r += gridDim.x * 256) {
        const int p = atomicAdd(&ws->cur[tgt[r] * CURW], 1);
        idxs[p] = r;
    }
}

// 4) per-(class,split) partial reduction. lane = dim, 8 rows in flight per wave,
//    idx list staged in LDS so the gather chain has no global-latency idx hop.
__global__ __launch_bounds__(256) void k_reduce(const float* __restrict__ emb,
                                                const int* __restrict__ idxs,
                                                const Ws* __restrict__ ws,
                                                float* __restrict__ part,
                                                float* __restrict__ part_ssq) {
    __shared__ int   sidx[STAGE];
    __shared__ float facc[4][DIM];
    __shared__ float fssq[4];
    const int bid  = blockIdx.x;
    const int c    = bid >> 2;          // class
    const int sp   = bid & (SPLIT - 1); // split slice
    const int t    = threadIdx.x;
    const int lane = t & 63;            // dim
    const int w    = t >> 6;            // wave 0..3
    const int cnt  = ws->counts[c];
    const int i0   = (cnt * sp) / SPLIT;
    const int i1   = (cnt * (sp + 1)) / SPLIT;
    const int base = ws->offs[c] + i0;
    const int m    = i1 - i0;

    float acc = 0.f, ssq = 0.f;
    for (int s0 = 0; s0 < m; s0 += STAGE) {
        const int mm = min(STAGE, m - s0);
        __syncthreads();
        for (int i = t; i < mm; i += 256) sidx[i] = idxs[base + s0 + i];
        __syncthreads();
        // wave w takes rows w, w+4, w+8, ... ; 8 independent gathers in flight
        int p = w;
        for (; p + 28 < mm; p += 32) {
            const int r0 = sidx[p];      const int r1 = sidx[p + 4];
            const int r2 = sidx[p + 8];  const int r3 = sidx[p + 12];
            const int r4 = sidx[p + 16]; const int r5 = sidx[p + 20];
            const int r6 = sidx[p + 24]; const int r7 = sidx[p + 28];
            const float v0 = emb[(size_t)r0 * DIM + lane];
            const float v1 = emb[(size_t)r1 * DIM + lane];
            const float v2 = emb[(size_t)r2 * DIM + lane];
            const float v3 = emb[(size_t)r3 * DIM + lane];
            const float v4 = emb[(size_t)r4 * DIM + lane];
            const float v5 = emb[(size_t)r5 * DIM + lane];
            const float v6 = emb[(size_t)r6 * DIM + lane];
            const float v7 = emb[(size_t)r7 * DIM + lane];
            acc += v0 + v1 + v2 + v3 + v4 + v5 + v6 + v7;
            ssq += v0 * v0 + v1 * v1 + v2 * v2 + v3 * v3
                 + v4 * v4 + v5 * v5 + v6 * v6 + v7 * v7;
        }
        for (; p < mm; p += 4) {
            const int r0 = sidx[p];
            const float v0 = emb[(size_t)r0 * DIM + lane];
            acc += v0;
            ssq += v0 * v0;
        }
    }
    facc[w][lane] = acc;
    for (int o = 32; o; o >>= 1) ssq += __shfl_down(ssq, o);
    if (lane == 0) fssq[w] = ssq;
    __syncthreads();
    if (t < DIM)
        part[bid * DIM + t] = facc[0][t] + facc[1][t] + facc[2][t] + facc[3][t];
    if (t == 0)
        part_ssq[bid] = fssq[0] + fssq[1] + fssq[2] + fssq[3];
}

// 4b) combine SPLIT partials -> mu, sq, per-class ssq and count*||mu||^2 terms
__global__ __launch_bounds__(64) void k_centers(Ws* ws,
                                                const float* __restrict__ part,
                                                const float* __restrict__ part_ssq,
                                                float* __restrict__ cls_ssq,
                                                float* __restrict__ cls_mt) {
    const int c = blockIdx.x;
    const int t = threadIdx.x;
    const int cnt = ws->counts[c];
    float v = 0.f;
    #pragma unroll
    for (int s = 0; s < SPLIT; ++s) v += part[(c * SPLIT + s) * DIM + t];
    const float m = v / (float)max(cnt, 1);
    ws->mu[c * DIM + t] = m;
    float p = m * m;
    for (int o = 32; o; o >>= 1) p += __shfl_down(p, o);
    if (t == 0) {
        ws->sq[c] = p;
        cls_mt[c] = cnt ? (float)cnt * p : 0.f;
        float s2 = 0.f;
        #pragma unroll
        for (int s = 0; s < SPLIT; ++s) s2 += part_ssq[c * SPLIT + s];
        cls_ssq[c] = s2;
    }
}

// 5) tiled pairwise-min over centers: 64x64 upper-triangular tiles, 4x4 micro-tile
#define TILE 64
#define NTA 16
#define NPAIR (NTA * (NTA + 1) / 2)  // 136
__global__ __launch_bounds__(256) void k_pairs(Ws* ws) {
    __shared__ float As[TILE][DIM + 4];
    __shared__ float Bst[DIM][TILE + 1];
    __shared__ float sqa_s[TILE], sqb_s[TILE];
    __shared__ int   pa_s[TILE], pb_s[TILE];
    __shared__ unsigned redm[4];

    int rem = blockIdx.x, ta = 0;
    while (rem >= NTA - ta) { rem -= NTA - ta; ++ta; }
    const int tb = ta + rem;
    const int tid = threadIdx.x;

    for (int i = tid; i < TILE * (DIM / 4); i += 256) {
        const int r = i >> 4, c4 = (i & 15) * 4;
        const int ga = ta * TILE + r;
        const int gb = tb * TILE + r;
        float4 va = make_float4(0.f, 0.f, 0.f, 0.f);
        float4 vb = make_float4(0.f, 0.f, 0.f, 0.f);
        if (ga < NCLS) va = *reinterpret_cast<const float4*>(&ws->mu[ga * DIM + c4]);
        if (gb < NCLS) vb = *reinterpret_cast<const float4*>(&ws->mu[gb * DIM + c4]);
        *reinterpret_cast<float4*>(&As[r][c4]) = va;
        Bst[c4 + 0][r] = vb.x; Bst[c4 + 1][r] = vb.y;
        Bst[c4 + 2][r] = vb.z; Bst[c4 + 3][r] = vb.w;
    }
    if (tid < TILE) {
        const int ga = ta * TILE + tid;
        const int gb = tb * TILE + tid;
        pa_s[tid]  = (ga < NCLS) ? (ws->counts[ga] > 0) : 0;
        sqa_s[tid] = (ga < NCLS) ? ws->sq[ga] : 0.f;
        pb_s[tid]  = (gb < NCLS) ? (ws->counts[gb] > 0) : 0;
        sqb_s[tid] = (gb < NCLS) ? ws->sq[gb] : 0.f;
    }
    __syncthreads();

    const int ty4 = (tid >> 4) * 4;
    const int tx4 = (tid & 15) * 4;
    float dot[4][4];
    #pragma unroll
    for (int i = 0; i < 4; ++i)
        #pragma unroll
        for (int j = 0; j < 4; ++j) dot[i][j] = 0.f;

    #pragma unroll 8
    for (int k = 0; k < DIM; ++k) {
        float av[4], bv[4];
        #pragma unroll
        for (int i = 0; i < 4; ++i) av[i] = As[ty4 + i][k];
        #pragma unroll
        for (int j = 0; j < 4; ++j) bv[j] = Bst[k][tx4 + j];
        #pragma unroll
        for (int i = 0; i < 4; ++i)
            #pragma unroll
            for (int j = 0; j < 4; ++j) dot[i][j] += av[i] * bv[j];
    }

    float best = 3.0e38f;
    #pragma unroll
    for (int i = 0; i < 4; ++i) {
        #pragma unroll
        for (int j = 0; j < 4; ++j) {
            const int ga = ta * TILE + ty4 + i;
            const int gb = tb * TILE + tx4 + j;
            const bool valid = pa_s[ty4 + i] && pb_s[tx4 + j] && (ga != gb);
            const float dd = sqa_s[ty4 + i] + sqb_s[tx4 + j] - 2.f * dot[i][j];
            if (valid) best = fminf(best, dd);
        }
    }
    for (int off = 32; off; off >>= 1) best = fminf(best, __shfl_down(best, off));
    if ((tid & 63) == 0) redm[tid >> 6] = fkey(best);
    __syncthreads();
    if (tid == 0) {
        unsigned m = redm[0];
        #pragma unroll
        for (int w = 1; w < 4; ++w) m = min(m, redm[w]);
        atomicMin(&ws->minkey, m);
    }
}

// 6) final: double-precision reduce of per-class terms + min distance
__global__ __launch_bounds__(256) void k_final(const Ws* ws,
                                               const float* __restrict__ cls_ssq,
                                               const float* __restrict__ cls_mt,
                                               float* out, int n) {
    __shared__ double sd[256], md[256];
    const int t = threadIdx.x;
    double a = 0.0, b = 0.0;
    for (int i = t; i < NCLS; i += 256) { a += (double)cls_ssq[i]; b += (double)cls_mt[i]; }
    sd[t] = a; md[t] = b;
    __syncthreads();
    for (int s = 128; s >= 1; s >>= 1) {
        if (t < s) { sd[t] += sd[t + s]; md[t] += md[t + s]; }
        __syncthreads();
    }
    if (t == 0) {
        out[0] = (float)((sd[0] - md[0]) / (double)n);
        out[1] = -funkey(ws->minkey);
    }
}

extern "C" void kernel_launch(void* const* d_in, const int* in_sizes, int n_in,
                              void* d_out, int out_size, void* d_ws, size_t ws_size,
                              hipStream_t stream) {
    const float* emb = (const float*)d_in[0];
    const int*   tgt = (const int*)d_in[1];
    float* out = (float*)d_out;
    const int n = in_sizes[1];        // 400000 rows
    Ws* ws = (Ws*)d_ws;
    char* p = (char*)d_ws + sizeof(Ws);
    int*   idxs     = (int*)p;                 p += (size_t)n * sizeof(int);
    float* part     = (float*)p;               p += (size_t)NCLS * SPLIT * DIM * sizeof(float);
    float* part_ssq = (float*)p;               p += (size_t)NCLS * SPLIT * sizeof(float);
    float* cls_ssq  = (float*)p;               p += (size_t)NCLS * sizeof(float);
    float* cls_mt   = (float*)p;

    k_zero   <<<4, 256, 0, stream>>>(ws);
    k_hist   <<<256, 256, 0, stream>>>(tgt, n, ws);
    k_scan   <<<1, 1024, 0, stream>>>(ws);
    k_scatter<<<1024, 256, 0, stream>>>(tgt, n, ws, idxs);
    k_reduce <<<NCLS * SPLIT, 256, 0, stream>>>(emb, idxs, ws, part, part_ssq);
    k_centers<<<NCLS, 64, 0, stream>>>(ws, part, part_ssq, cls_ssq, cls_mt);
    k_pairs  <<<NPAIR, 256, 0, stream>>>(ws);
    k_final  <<<1, 256, 0, stream>>>(ws, cls_ssq, cls_mt, out, n);
}